// Round 5
// baseline (133.119 us; speedup 1.0000x reference)
//
#include <hip/hip_runtime.h>
#include <math.h>

#define B_   8
#define T_   12
#define BT   96      // B*T
#define N_   1000
#define FIN  64
#define H_   8
#define FOUT 16
#define HF   128     // H*FOUT
#define E_   8000

typedef unsigned short u16;
typedef unsigned int   u32;
typedef __attribute__((ext_vector_type(8))) short  short8;   // 8 bf16 (4 VGPR)
typedef __attribute__((ext_vector_type(4))) float  float4v;  // MFMA acc

__device__ __forceinline__ float bf2f(u16 u) {
    return __uint_as_float(((u32)u) << 16);
}
__device__ __forceinline__ void unpack2(u32 q, float& lo, float& hi) {
    lo = __uint_as_float(q << 16);
    hi = __uint_as_float(q & 0xffff0000u);
}
__device__ __forceinline__ u16 f2bf(float f) {
    u32 x = __float_as_uint(f);
    u32 r = (x + 0x7fffu + ((x >> 16) & 1u)) >> 16;   // RNE
    return (u16)r;
}
__device__ __forceinline__ u32 pack2bf(float lo, float hi) {
    return (u32)f2bf(lo) | ((u32)f2bf(hi) << 16);
}

// Fragment-permuted W' layout: element (row r, col c) of the 272x64 W' lives
// at u16 index (((r>>4)*8 + (c>>5)*4 + ((c>>3)&3))*16 + (r&15))*8 + (c&7).
// => tile t / lane (m,q) reads its two 16B MFMA fragments at LDS bytes
// t*2048 + q*256 + m*16  and  t*2048 + 1024 + q*256 + m*16: a wave's 64
// lanes cover 64 consecutive 16B chunks -> conflict-free ds_read_b128.
__device__ __forceinline__ int wpos(int r, int c) {
    return (((r >> 4) * 8 + (c >> 5) * 4 + ((c >> 3) & 3)) * 16 + (r & 15)) * 8
           + (c & 7);
}

// ---------------------------------------------------------------------------
// Workspace carve (float-element offsets).
// ---------------------------------------------------------------------------
#define OFF_FLAGS   0         // 4 ints
#define OFF_OFFS    264       // 1004 ints
#define OFF_CSR     1268      // 8000 ints (stores src*BT, grouped by target)
#define OFF_ST      17972     // 1536000 sT fp32 [n][bt][16]
#define OFF_PROJ    1553972   // projT bf16 [n][bt][128] = 12.288M u16
#define OFF_SKIP    7697972   // skipT bf16 [n][bt][128]

// ---------------------------------------------------------------------------
// K1: MFMA GEMM  C[96000 x 272] = X[96000 x 64] . W'^T.
// Each GEMM block self-probes the x dtype and builds W' (proj | skip |
// aS-fold | aT-fold) directly in LDS from the raw L2-hot weights.
// Block 0 builds the CSR + writes flags; its scan is now a SINGLE-WAVE shfl
// scan (3 barriers total vs ~20 Hillis-Steele rounds) so the CSR block no
// longer straggles the dispatch while contended with co-resident GEMM blocks.
// GEMM = blocks 1..750.
// ---------------------------------------------------------------------------
__global__ __launch_bounds__(512) void k_mfma(const void* __restrict__ xin,
                                              const void* __restrict__ Wp,
                                              const void* __restrict__ Ws,
                                              const void* __restrict__ as_,
                                              const void* __restrict__ at_,
                                              const u32* __restrict__ ew,
                                              int* __restrict__ flags,
                                              u16* __restrict__ projT,
                                              u16* __restrict__ skipT,
                                              float* __restrict__ sT,
                                              int* __restrict__ offs,
                                              int* __restrict__ csrS)
{
    __shared__ __align__(16) unsigned char smemRaw[34816];

    const int tid = threadIdx.x;

    if (blockIdx.x == 0) {
        // ---- probes + CSR build (1 block, overlapped with GEMM blocks) ----
        int* cnt = (int*)smemRaw;          // [1000]
        int* cur = cnt + 1000;             // [1000]

        int pred = 0;
        if (tid < 256) {   // bf16-vs-fp32 probe on x
            const u32 w = ((const u32*)xin)[tid];
            const int e = (int)((w >> 7) & 0xFFu);
            pred = (e == 0 || (e >= 95 && e <= 140)) ? 1 : 0;
        }
        const int votes = __syncthreads_count(pred);
        u32 o = 0;
        for (int i = 2 * tid + 1; i < 16000; i += 1024) o |= ew[i];
        const u32 orAll = (u32)__syncthreads_or((int)o);
        const bool i64 = (orAll == 0u);
        if (tid == 0) {
            flags[0] = (votes >= 160) ? 1 : 0;
            flags[1] = i64 ? 1 : 0;
        }

        for (int i = tid; i < N_; i += 512) cnt[i] = 0;
        __syncthreads();
        for (int e = tid; e < E_; e += 512) {
            const int t = i64 ? (int)ew[2 * (E_ + e)] : (int)ew[E_ + e];
            atomicAdd(&cnt[t], 1);
        }
        __syncthreads();
        // single-wave exclusive scan over 1000 counts: lane l owns 16 idx
        if (tid < 64) {
            int loc[16];
            int s = 0;
#pragma unroll
            for (int i = 0; i < 16; i++) {
                const int idx = tid * 16 + i;
                const int v = (idx < N_) ? cnt[idx] : 0;
                loc[i] = s;              // lane-local exclusive prefix
                s += v;
            }
            int run = s;                 // wave inclusive scan of lane sums
#pragma unroll
            for (int d = 1; d < 64; d <<= 1) {
                const int up = __shfl_up(run, d, 64);
                if (tid >= d) run += up;
            }
            const int excl = run - s;    // wave exclusive prefix
#pragma unroll
            for (int i = 0; i < 16; i++) {
                const int idx = tid * 16 + i;
                if (idx < N_) {
                    const int v = excl + loc[i];
                    offs[idx] = v;
                    cur[idx]  = v;
                }
            }
            if (tid == 0) offs[N_] = E_;
        }
        __syncthreads();
        for (int e = tid; e < E_; e += 512) {
            const int s = i64 ? (int)ew[2 * e] : (int)ew[e];
            const int t = i64 ? (int)ew[2 * (E_ + e)] : (int)ew[E_ + e];
            const int pos = atomicAdd(&cur[t], 1);
            csrS[pos] = s * BT;              // pre-scaled for k_att
        }
        return;
    }

    // ---- GEMM path (blocks 1..750) ----
    // self-probe x dtype (identical criterion to block 0; deterministic)
    int pred = 0;
    if (tid < 256) {
        const u32 w = ((const u32*)xin)[tid];
        const int e = (int)((w >> 7) & 0xFFu);
        pred = (e == 0 || (e >= 95 && e <= 140)) ? 1 : 0;
    }
    const int votes = __syncthreads_count(pred);
    const bool bf = votes >= 160;

    const int wid  = tid >> 6;
    const int lid  = tid & 63;
    const int m    = lid & 15;
    const int q    = lid >> 4;
    const int base = (blockIdx.x - 1) * 128 + wid * 16;

    // issue X load early; W' build below hides its latency
    short8 x0, x1;   // X fragment (B-operand)
    {
        const size_t xoff = (size_t)(base + m) * FIN + q * 8;
        if (bf) {
            const u16* xp = (const u16*)xin + xoff;
            x0 = *reinterpret_cast<const short8*>(xp);
            x1 = *reinterpret_cast<const short8*>(xp + 32);
        } else {
            const float* xp = (const float*)xin + xoff;
            union { short8 v; u16 e[8]; } p0, p1;
#pragma unroll
            for (int i = 0; i < 8; i++) {
                p0.e[i] = f2bf(xp[i]);
                p1.e[i] = f2bf(xp[i + 32]);
            }
            x0 = p0.v;
            x1 = p1.v;
        }
    }

    // build W' (permuted) in LDS — vectorized: 8 cols per iter
    u16* wl = (u16*)smemRaw;
    if (bf) {
        const short8* wpv = (const short8*)Wp;
        const short8* wsv = (const short8*)Ws;
        for (int i8 = tid; i8 < (HF * FIN) / 8; i8 += 512) {
            const int r = i8 >> 3, c0 = (i8 & 7) * 8;
            *reinterpret_cast<short8*>(wl + wpos(r, c0))       = wpv[i8];
            *reinterpret_cast<short8*>(wl + wpos(128 + r, c0)) = wsv[i8];
        }
    } else {
        const float4* wpv = (const float4*)Wp;
        const float4* wsv = (const float4*)Ws;
        for (int i8 = tid; i8 < (HF * FIN) / 8; i8 += 512) {
            const int r = i8 >> 3, c0 = (i8 & 7) * 8;
            float4 va = wpv[i8 * 2], vb = wpv[i8 * 2 + 1];
            union { short8 v; u16 e[8]; } p;
            p.e[0] = f2bf(va.x); p.e[1] = f2bf(va.y);
            p.e[2] = f2bf(va.z); p.e[3] = f2bf(va.w);
            p.e[4] = f2bf(vb.x); p.e[5] = f2bf(vb.y);
            p.e[6] = f2bf(vb.z); p.e[7] = f2bf(vb.w);
            *reinterpret_cast<short8*>(wl + wpos(r, c0)) = p.v;
            va = wsv[i8 * 2]; vb = wsv[i8 * 2 + 1];
            p.e[0] = f2bf(va.x); p.e[1] = f2bf(va.y);
            p.e[2] = f2bf(va.z); p.e[3] = f2bf(va.w);
            p.e[4] = f2bf(vb.x); p.e[5] = f2bf(vb.y);
            p.e[6] = f2bf(vb.z); p.e[7] = f2bf(vb.w);
            *reinterpret_cast<short8*>(wl + wpos(128 + r, c0)) = p.v;
        }
    }
    __syncthreads();
    {   // a-fold: thread -> (h, k); writes tile-16 region (disjoint from reads)
        const int h = tid >> 6, k = tid & 63;
        float s1 = 0.f, s2 = 0.f;
#pragma unroll
        for (int f = 0; f < FOUT; f++) {
            const float w  = bf2f(wl[wpos(h * FOUT + f, k)]);
            const float a1 = bf ? bf2f(((const u16*)as_)[h * FOUT + f])
                                : ((const float*)as_)[h * FOUT + f];
            const float a2 = bf ? bf2f(((const u16*)at_)[h * FOUT + f])
                                : ((const float*)at_)[h * FOUT + f];
            s1 = fmaf(a1, w, s1);
            s2 = fmaf(a2, w, s2);
        }
        wl[wpos(256 + h, k)] = f2bf(s1);   // aS rows
        wl[wpos(264 + h, k)] = f2bf(s2);   // aT rows
    }

    // per-lane output row: row = bt*1000 + n  ->  ob = n*BT + bt
    const u32 rowm = (u32)(base + m);
    const u32 bt   = rowm / 1000u;
    const u32 n    = rowm - bt * 1000u;
    const u32 obm  = n * BT + bt;

    u16* projBase = projT + (size_t)obm * HF;
    u16* skipBase = skipT + (size_t)obm * HF;

    __syncthreads();   // W' complete

    const char* WL = (const char*)smemRaw;
    const int   fo = q * 256 + m * 16;   // per-lane fragment byte offset

#pragma unroll
    for (int t = 0; t < 16; t++) {
        const short8 b0 = *reinterpret_cast<const short8*>(WL + t * 2048 + fo);
        const short8 b1 = *reinterpret_cast<const short8*>(WL + t * 2048 + 1024 + fo);
        float4v acc = {0.f, 0.f, 0.f, 0.f};
        acc = __builtin_amdgcn_mfma_f32_16x16x32_bf16(b0, x0, acc, 0, 0, 0);
        acc = __builtin_amdgcn_mfma_f32_16x16x32_bf16(b1, x1, acc, 0, 0, 0);

        u16* dst = (t < 8) ? projBase : skipBase;
        const int col = ((t < 8) ? t : (t - 8)) * 16 + q * 4;
        uint2 v;
        v.x = pack2bf(acc[0], acc[1]);
        v.y = pack2bf(acc[2], acc[3]);
        *reinterpret_cast<uint2*>(dst + col) = v;          // 8B aligned store
    }

    {   // score tile: W' rows 256..271 -> sT cols 0..15 (aS | aT)
        const short8 b0 = *reinterpret_cast<const short8*>(WL + 16 * 2048 + fo);
        const short8 b1 = *reinterpret_cast<const short8*>(WL + 16 * 2048 + 1024 + fo);
        float4v acc = {0.f, 0.f, 0.f, 0.f};
        acc = __builtin_amdgcn_mfma_f32_16x16x32_bf16(b0, x0, acc, 0, 0, 0);
        acc = __builtin_amdgcn_mfma_f32_16x16x32_bf16(b1, x1, acc, 0, 0, 0);
        *reinterpret_cast<float4v*>(sT + (size_t)obm * 16 + q * 4) = acc; // 16B
    }
}

// ---------------------------------------------------------------------------
// K2: attention gather, 2 bt per wave, XCD-pinned bt-slices. grid 12000.
// Block decode: b = (wgid&7)*1500 + (wgid>>3); by = b/1000; n = b%1000 —
// each bt-slice's ~3.5 MB working set pins to <=2 XCD L2s (R4: -12 us).
// NEW (R5): no LDS, no __syncthreads — the 64-edge CSR tile lives in
// REGISTERS (one coalesced load/lane, redistributed via __shfl; lanes >=
// cnt hold csr[cnt-1], so raw shfl indices are safely clamped by
// construction). 8-edge passes issue both sT gathers AND all 8 (weight-
// independent) proj-gather addresses up front, so the two ~200cy gather
// latencies overlap instead of chaining -> per-wave critical path ~2.5x
// shorter. Roles unchanged: OUTPUT lane j2 owns bt half (j2>>5), cols
// 4*(j2&31)..+3; WEIGHT lane j2 computes exp for edge-slots (j2>>4) and
// (j2>>4)+4, bt half ((j2>>3)&1), head (j2&7).
// No global-max subtraction: softmax is shift-invariant and scores are
// structurally bounded (|s| <~ 15 << 88), so exp cannot overflow.
// ---------------------------------------------------------------------------
__global__ __launch_bounds__(256) void k_att(const u16* __restrict__ projT,
                                             const u16* __restrict__ skipT,
                                             const float* __restrict__ sT,
                                             const int* __restrict__ offs,
                                             const int* __restrict__ csrS,
                                             const int* __restrict__ flags,
                                             void* __restrict__ out)
{
    const int wg  = blockIdx.x;                    // 0..11999
    const int b   = (wg & 7) * 1500 + (wg >> 3);   // XCD-pinned remap
    const int by  = b / 1000;                      // bt-slice 0..11
    const int n   = b - by * 1000;
    const int tid = threadIdx.x;
    const int btp = by * 4 + (tid >> 6);           // 0..47
    const int bt0 = btp * 2;
    const int j2  = tid & 63;
    // weight role
    const int sw  = j2 >> 4;          // edge slot 0..3 (and +4)
    const int bw  = (j2 >> 3) & 1;    // bt half
    const int hw  = j2 & 7;           // head
    // output role
    const int bo  = j2 >> 5;          // bt half
    const int lo5 = j2 & 31;
    const int c0  = lo5 * 4;          // cols c0..c0+3 (single head)
    const int ho  = lo5 >> 2;         // head of those cols

    const int bt_w = bt0 + bw;
    const int bt_o = bt0 + bo;
    const float st_w  = sT[((size_t)n * BT + bt_w) * 16 + 8 + hw];
    const int   sboff = bt_w * 16 + hw;           // score addr = csr*16 + sboff
    const u32   oboff = (u32)bt_o * HF + c0;      // proj  addr = csr*128 + oboff

    float y0 = 0.f, y1 = 0.f, y2 = 0.f, y3 = 0.f, den = 0.f;
    const int e0 = offs[n], e1 = offs[n + 1];

    for (int base = e0; base < e1; base += 64) {
        const int cnt = min(64, e1 - base);
        // CSR tile -> registers (coalesced); lanes >= cnt hold csr[cnt-1]
        const int rc = csrS[base + min(j2, cnt - 1)];

        for (int i0 = 0; i0 < cnt; i0 += 8) {
            const int eA = i0 + sw;          // <= 59
            const int eB = i0 + 4 + sw;      // <= 63
            // issue both sT gathers up front
            const int sA = __shfl(rc, eA, 64);
            const int sB = __shfl(rc, eB, 64);
            const float ssA = sT[(size_t)sA * 16 + sboff];
            const float ssB = sT[(size_t)sB * 16 + sboff];
            // issue all 8 proj gathers (addresses independent of weights)
            uint2 pq[8];
#pragma unroll
            for (int k = 0; k < 8; k++) {
                const int sk_ = __shfl(rc, i0 + k, 64);   // i0+k <= 63
                pq[k] = *(const uint2*)(projT + (size_t)sk_ * HF + oboff);
            }
            float scA = ssA + st_w;
            float scB = ssB + st_w;
            scA = fmaxf(scA, 0.2f * scA);               // leaky_relu(0.2)
            scB = fmaxf(scB, 0.2f * scB);
            const float wmA = (eA < cnt) ? __expf(scA) : 0.f;
            const float wmB = (eB < cnt) ? __expf(scB) : 0.f;
#pragma unroll
            for (int k = 0; k < 8; k++) {
                const float wk = (k < 4)
                    ? __shfl(wmA, k * 16 + bo * 8 + ho, 64)
                    : __shfl(wmB, (k - 4) * 16 + bo * 8 + ho, 64);
                float f0, f1, f2, f3;
                unpack2(pq[k].x, f0, f1);
                unpack2(pq[k].y, f2, f3);
                den += wk;
                y0 = fmaf(wk, f0, y0);
                y1 = fmaf(wk, f1, y1);
                y2 = fmaf(wk, f2, y2);
                y3 = fmaf(wk, f3, y3);
            }
        }
    }

    const float rden = __builtin_amdgcn_rcpf(den + 1e-16f);
    float sk0, sk1, sk2, sk3;
    {
        const uint2 sq = *(const uint2*)(skipT + ((size_t)n * BT + bt_o) * HF + c0);
        unpack2(sq.x, sk0, sk1);
        unpack2(sq.y, sk2, sk3);
    }
    float o0 = fmaf(y0, rden, sk0);
    float o1 = fmaf(y1, rden, sk1);
    float o2 = fmaf(y2, rden, sk2);
    float o3 = fmaf(y3, rden, sk3);
    o0 = o0 > 0.f ? o0 : __expf(o0) - 1.0f;             // ELU (bf16-exact enough)
    o1 = o1 > 0.f ? o1 : __expf(o1) - 1.0f;
    o2 = o2 > 0.f ? o2 : __expf(o2) - 1.0f;
    o3 = o3 > 0.f ? o3 : __expf(o3) - 1.0f;

    const size_t ob = ((size_t)bt_o * N_ + n) * HF + c0;
    if (flags[0]) {
        uint2 v;
        v.x = pack2bf(o0, o1);
        v.y = pack2bf(o2, o3);
        *reinterpret_cast<uint2*>((u16*)out + ob) = v;
    } else {
        *reinterpret_cast<float4*>((float*)out + ob) = make_float4(o0, o1, o2, o3);
    }
}

// ---------------------------------------------------------------------------
extern "C" void kernel_launch(void* const* d_in, const int* in_sizes, int n_in,
                              void* d_out, int out_size, void* d_ws, size_t ws_size,
                              hipStream_t stream)
{
    const void* x   = d_in[0];
    const u32*  ew  = (const u32*)d_in[1];
    const void* Wp  = d_in[2];
    const void* as_ = d_in[3];
    const void* at_ = d_in[4];
    const void* Ws  = d_in[5];

    float* ws    = (float*)d_ws;
    int*   flags = (int*)(ws + OFF_FLAGS);
    int*   offs  = (int*)(ws + OFF_OFFS);
    int*   csrS  = (int*)(ws + OFF_CSR);
    float* sT    = ws + OFF_ST;
    u16*   projT = (u16*)(ws + OFF_PROJ);
    u16*   skipT = (u16*)(ws + OFF_SKIP);

    k_mfma<<<751, 512, 0, stream>>>(x, Wp, Ws, as_, at_, ew, flags,
                                    projT, skipT, sT, offs, csrS);
    k_att <<<12000, 256, 0, stream>>>(projT, skipT, sT,
                                      offs, csrS, flags, d_out);
}